// Round 12
// baseline (313.147 us; speedup 1.0000x reference)
//
#include <hip/hip_runtime.h>
#include <hip/hip_bf16.h>

typedef short s8v  __attribute__((ext_vector_type(8)));
typedef float f16v __attribute__((ext_vector_type(16)));

__device__ __forceinline__ unsigned short f2bf(float x) {   // RTN-even
    unsigned u = __float_as_uint(x);
    unsigned r = ((u >> 16) & 1u) + 0x7FFFu;
    return (unsigned short)((u + r) >> 16);
}
__device__ __forceinline__ float bf2f(unsigned short h) {
    return __uint_as_float(((unsigned)h) << 16);
}

// ---------------- fused prep: bprep | hist | x0 | relctx ----------------
// blocks [0,640): B-pack; [640,1422): hist; [1422,7672): x0; [7672,7872): relctx
__global__ __launch_bounds__(256) void prep_kernel(
    const float* __restrict__ basis1, const float* __restrict__ root1,
    const float* __restrict__ basis2, const float* __restrict__ root2,
    unsigned short* __restrict__ Bp1h, unsigned short* __restrict__ Bp1l,
    unsigned short* __restrict__ Bp2h, unsigned short* __restrict__ Bp2l,
    const int* __restrict__ edge_index, int* __restrict__ deg, int E,
    const float* __restrict__ tab, const int* __restrict__ entity,
    unsigned short* __restrict__ X0h, unsigned short* __restrict__ X0l, int N,
    const float* __restrict__ DAD, const float* __restrict__ rtab,
    const float* __restrict__ Wrel, float* __restrict__ Rc, int NR)
{
    __shared__ float smem[384];
    const int b = blockIdx.x, tid = threadIdx.x;

    if (b < 640) {                       // ---- B prep ----
        int layer = b >= 320;
        int idx = (layer ? b - 320 : b) * 256 + tid;
        int n = idx & 127, k = idx >> 7;
        const float* basis = layer ? basis2 : basis1;
        const float* root  = layer ? root2  : root1;
        float v = (k < 512) ? basis[((k & 3) << 14) + ((k >> 2) << 7) + n]
                            : root[((k - 512) << 7) + n];
        unsigned short h = f2bf(v);
        unsigned short l = f2bf(v - bf2f(h));
        size_t pos = (((size_t)(k >> 3) * 128) + n) * 8 + (k & 7);
        (layer ? Bp2h : Bp1h)[pos] = h;
        (layer ? Bp2l : Bp1l)[pos] = l;
    } else if (b < 1422) {               // ---- hist ----
        int e = (b - 640) * 256 + tid;
        if (e < E) atomicAdd(&deg[edge_index[E + e]], 1);
    } else if (b < 7672) {               // ---- X0 = tab[entity] hi/lo ----
        int idx = (b - 1422) * 256 + tid;
        int n = idx >> 5, l = idx & 31;
        if (n < N) {
            int src = entity[n];
            float4 v = *(const float4*)&tab[(size_t)src * 128 + l * 4];
            ushort4 h, lo;
            h.x = f2bf(v.x); lo.x = f2bf(v.x - bf2f(h.x));
            h.y = f2bf(v.y); lo.y = f2bf(v.y - bf2f(h.y));
            h.z = f2bf(v.z); lo.z = f2bf(v.z - bf2f(h.z));
            h.w = f2bf(v.w); lo.w = f2bf(v.w - bf2f(h.w));
            *(ushort4*)&X0h[(size_t)n * 128 + l * 4] = h;
            *(ushort4*)&X0l[(size_t)n * 128 + l * 4] = lo;
        }
    } else {                             // ---- relctx (256-thread variant) ----
        float* part = smem;              // [2][128]
        float* r1s  = smem + 256;        // [128]
        int r = b - 7672;
        int o = tid & 127, q = tid >> 7;
        float s = 0.f;
        for (int j = q; j < NR; j += 2)
            s = fmaf(DAD[r * NR + j], rtab[j * 128 + o], s);
        part[q * 128 + o] = s;
        __syncthreads();
        if (tid < 128) r1s[tid] = part[tid] + part[128 + tid];
        __syncthreads();
        float s2 = 0.f;
        #pragma unroll 8
        for (int k = q * 64; k < q * 64 + 64; ++k)
            s2 = fmaf(r1s[k], Wrel[k * 128 + o], s2);
        part[q * 128 + o] = s2;
        __syncthreads();
        if (tid < 128)
            Rc[r * 128 + tid] = fmaxf(part[tid] + part[128 + tid], 0.f);
    }
}

// ---------------- CSR scan ----------------
__global__ __launch_bounds__(1024) void scanA_kernel(
    const int* __restrict__ deg, int* __restrict__ row_start,
    int* __restrict__ btot, int N)
{
    __shared__ int wtot[16];
    __shared__ int woff[16];
    const int tid = threadIdx.x, lane = tid & 63, wid = tid >> 6;
    int i = blockIdx.x * 1024 + tid;
    int v = (i < N) ? deg[i] : 0;
    int x = v;
    #pragma unroll
    for (int d = 1; d < 64; d <<= 1) {
        int t = __shfl_up(x, d, 64);
        if (lane >= d) x += t;
    }
    if (lane == 63) wtot[wid] = x;
    __syncthreads();
    if (wid == 0 && lane < 16) {
        int s = wtot[lane];
        int y = s;
        #pragma unroll
        for (int d = 1; d < 16; d <<= 1) {
            int t = __shfl_up(y, d, 16);
            if (lane >= d) y += t;
        }
        woff[lane] = y - s;
        if (lane == 15) btot[blockIdx.x] = y;
    }
    __syncthreads();
    if (i < N) row_start[i] = woff[wid] + (x - v);
}

__global__ __launch_bounds__(64) void scanB_kernel(
    const int* __restrict__ btot, int* __restrict__ boff,
    int* __restrict__ row_start, int nB, int N)
{
    int t = threadIdx.x;
    int v = (t < nB) ? btot[t] : 0;
    int x = v;
    #pragma unroll
    for (int d = 1; d < 64; d <<= 1) {
        int u = __shfl_up(x, d, 64);
        if (t >= d) x += u;
    }
    if (t < nB) boff[t] = x - v;
    if (t == nB - 1) row_start[N] = x;
}

__global__ __launch_bounds__(1024) void scanC_kernel(
    int* __restrict__ row_start, int* __restrict__ cursor,
    const int* __restrict__ boff, int N)
{
    int i = blockIdx.x * 1024 + threadIdx.x;
    if (i < N) {
        int r = row_start[i] + boff[blockIdx.x];
        row_start[i] = r;
        cursor[i]    = r;
    }
}

__global__ __launch_bounds__(256) void fill_kernel(
    const int* __restrict__ edge_index, const int* __restrict__ edge_type,
    const float* __restrict__ edge_norm, int* __restrict__ cursor,
    const float* __restrict__ att1, const float* __restrict__ att2,
    int* __restrict__ src_s, float4* __restrict__ an1, float4* __restrict__ an2, int E)
{
    int e = blockIdx.x * 256 + threadIdx.x;
    if (e >= E) return;
    int dst = edge_index[E + e];
    int et  = edge_type[e];
    float n = edge_norm[e];
    int pos = atomicAdd(&cursor[dst], 1);
    src_s[pos] = edge_index[e];
    float4 a1 = *(const float4*)&att1[(size_t)et * 4];
    float4 a2 = *(const float4*)&att2[(size_t)et * 4];
    an1[pos] = make_float4(n * a1.x, n * a1.y, n * a1.z, n * a1.w);
    an2[pos] = make_float4(n * a2.x, n * a2.y, n * a2.z, n * a2.w);
}

// ---------------- FUSED layer: Xout = relu([agg(X)|X] @ B + bias) ----------------
// Block = 32 nodes, 256 threads. Phase A: all-4-node interleaved edge gather
// (16 loads in flight per group) + X hi/lo rows -> LDS fragment-packed
// (slot = n ^ (kh&31)); one barrier. Phase B: barrier-free MFMA stream, B from
// packed global tables double-buffered in registers.
__global__ __launch_bounds__(256) void layer_kernel(
    const unsigned short* __restrict__ Xh,    // [N,128] bf16 hi
    const unsigned short* __restrict__ Xl,    // [N,128] bf16 lo
    const int* __restrict__ row_start,
    const int* __restrict__ src_s,
    const float4* __restrict__ an,
    const unsigned short* __restrict__ Bph,   // packed [80][128][8]
    const unsigned short* __restrict__ Bpl,
    const float* __restrict__ bias,
    unsigned short* __restrict__ Xoh,         // [N,128] bf16 hi out
    unsigned short* __restrict__ Xol,         // [N,128] bf16 lo out
    int N)
{
    __shared__ unsigned short Whi[80 * 32 * 8];   // 40 KB
    __shared__ unsigned short Wlo[16 * 32 * 8];   // 8 KB

    const int tid   = threadIdx.x;
    const int node0 = blockIdx.x * 32;

    // ---- phase A1: interleaved gather for 4 nodes per 32-lane group ----
    {
        int g = tid >> 5, l = tid & 31;     // lane l covers dims 4l..4l+3
        int nb = node0 + g * 4;
        int s0a[4], s1a[4];
        #pragma unroll
        for (int i = 0; i < 4; ++i) {
            int gn = nb + i;
            bool ok = gn < N;
            s0a[i] = ok ? row_start[gn] : 0;
            s1a[i] = ok ? row_start[gn + 1] : 0;
        }
        float acc[4][4][4];                 // [node][d][b]
        #pragma unroll
        for (int i = 0; i < 4; ++i)
            #pragma unroll
            for (int d = 0; d < 4; ++d)
                #pragma unroll
                for (int c = 0; c < 4; ++c) acc[i][d][c] = 0.f;

        int need = 0;
        #pragma unroll
        for (int i = 0; i < 4; ++i) need = max(need, s1a[i] - s0a[i]);

        for (int p = 0; p < need; p += 4) {
            #pragma unroll
            for (int i = 0; i < 4; ++i) {
                int q0 = s0a[i] + p;
                if (q0 < s1a[i]) {
                    int se = s1a[i] - 1;
                    int q1 = min(q0 + 1, se);
                    int q2 = min(q0 + 2, se);
                    int q3 = min(q0 + 3, se);
                    int sA = src_s[q0], sB = src_s[q1];
                    int sC = src_s[q2], sD = src_s[q3];
                    float4 aA = an[q0], aB = an[q1];
                    float4 aC = an[q2], aD = an[q3];
                    if (q0 + 1 > se) aB = make_float4(0.f, 0.f, 0.f, 0.f);
                    if (q0 + 2 > se) aC = make_float4(0.f, 0.f, 0.f, 0.f);
                    if (q0 + 3 > se) aD = make_float4(0.f, 0.f, 0.f, 0.f);
                    ushort4 hA = *(const ushort4*)&Xh[(size_t)sA * 128 + (l << 2)];
                    ushort4 hB = *(const ushort4*)&Xh[(size_t)sB * 128 + (l << 2)];
                    ushort4 hC = *(const ushort4*)&Xh[(size_t)sC * 128 + (l << 2)];
                    ushort4 hD = *(const ushort4*)&Xh[(size_t)sD * 128 + (l << 2)];
                    float xsA[4] = {bf2f(hA.x), bf2f(hA.y), bf2f(hA.z), bf2f(hA.w)};
                    float xsB[4] = {bf2f(hB.x), bf2f(hB.y), bf2f(hB.z), bf2f(hB.w)};
                    float xsC[4] = {bf2f(hC.x), bf2f(hC.y), bf2f(hC.z), bf2f(hC.w)};
                    float xsD[4] = {bf2f(hD.x), bf2f(hD.y), bf2f(hD.z), bf2f(hD.w)};
                    #pragma unroll
                    for (int d = 0; d < 4; ++d) {
                        acc[i][d][0] = fmaf(aA.x, xsA[d], fmaf(aB.x, xsB[d], fmaf(aC.x, xsC[d], fmaf(aD.x, xsD[d], acc[i][d][0]))));
                        acc[i][d][1] = fmaf(aA.y, xsA[d], fmaf(aB.y, xsB[d], fmaf(aC.y, xsC[d], fmaf(aD.y, xsD[d], acc[i][d][1]))));
                        acc[i][d][2] = fmaf(aA.z, xsA[d], fmaf(aB.z, xsB[d], fmaf(aC.z, xsC[d], fmaf(aD.z, xsD[d], acc[i][d][2]))));
                        acc[i][d][3] = fmaf(aA.w, xsA[d], fmaf(aB.w, xsB[d], fmaf(aC.w, xsC[d], fmaf(aD.w, xsD[d], acc[i][d][3]))));
                    }
                }
            }
        }
        // store: k = 16l + 4d + b -> kh = 2l + (d>>1), j = (d&1)*4 + b
        #pragma unroll
        for (int i = 0; i < 4; ++i) {
            int n = g * 4 + i;
            float inv = 1.0f / fmaxf((float)(s1a[i] - s0a[i]), 1.0f);
            #pragma unroll
            for (int d = 0; d < 4; ++d) {
                int kh   = 2 * l + (d >> 1);
                int slot = n ^ (kh & 31);
                ushort4 h;
                h.x = f2bf(acc[i][d][0] * inv);
                h.y = f2bf(acc[i][d][1] * inv);
                h.z = f2bf(acc[i][d][2] * inv);
                h.w = f2bf(acc[i][d][3] * inv);
                *(ushort4*)&Whi[(kh * 32 + slot) * 8 + (d & 1) * 4] = h;
            }
        }
    }

    // ---- phase A2: X hi/lo rows (k 512..639) straight copy, kh 64..79 ----
    {
        int r  = tid >> 3;                  // 0..31
        int kq = (tid & 7) * 16;            // 0..112
        int gn = node0 + r;
        #pragma unroll
        for (int i = 0; i < 2; ++i) {
            int kh   = 64 + (tid & 7) * 2 + i;
            int slot = r ^ (kh & 31);
            s8v h8 = {0,0,0,0,0,0,0,0}, l8 = {0,0,0,0,0,0,0,0};
            if (gn < N) {
                h8 = *(const s8v*)&Xh[(size_t)gn * 128 + kq + i * 8];
                l8 = *(const s8v*)&Xl[(size_t)gn * 128 + kq + i * 8];
            }
            *(s8v*)&Whi[(kh * 32 + slot) * 8] = h8;
            *(s8v*)&Wlo[((kh - 64) * 32 + slot) * 8] = l8;
        }
    }
    __syncthreads();

    // ---- phase B: barrier-free MFMA stream ----
    const int lane = tid & 63, wv = tid >> 6;
    const int m    = lane & 31;
    const int kh8  = lane >> 5;
    const int c0   = wv << 5;

    f16v acc;
    #pragma unroll
    for (int i = 0; i < 16; ++i) acc[i] = 0.f;

    s8v Bb[2][8];
    auto loadB4 = [&](int g, int buf) {
        #pragma unroll
        for (int q = 0; q < 4; ++q) {
            int khg = (g * 4 + q) * 2 + kh8;
            size_t off = ((size_t)khg * 128 + c0 + m) * 8;
            Bb[buf][q * 2 + 0] = *(const s8v*)&Bph[off];
            Bb[buf][q * 2 + 1] = *(const s8v*)&Bpl[off];
        }
    };
    loadB4(0, 0);

    #pragma unroll
    for (int g = 0; g < 10; ++g) {
        int buf = g & 1;
        if (g < 9) loadB4(g + 1, buf ^ 1);
        #pragma unroll
        for (int q = 0; q < 4; ++q) {
            int s    = g * 4 + q;
            int khg  = s * 2 + kh8;
            int slot = m ^ (khg & 31);
            s8v aH = *(const s8v*)&Whi[(khg * 32 + slot) * 8];
            if (s >= 32) {
                s8v aL = *(const s8v*)&Wlo[((khg - 64) * 32 + slot) * 8];
                acc = __builtin_amdgcn_mfma_f32_32x32x16_bf16(aL, Bb[buf][q*2], acc, 0, 0, 0);
            }
            acc = __builtin_amdgcn_mfma_f32_32x32x16_bf16(aH, Bb[buf][q*2+1], acc, 0, 0, 0);
            acc = __builtin_amdgcn_mfma_f32_32x32x16_bf16(aH, Bb[buf][q*2+0], acc, 0, 0, 0);
        }
    }

    // epilogue: 32x32 C/D: col = lane&31, row = (reg&3) + 8*(reg>>2) + 4*(lane>>5)
    int gc = c0 + m;
    float bv = bias[gc];
    const int rbase = kh8 << 2;
    #pragma unroll
    for (int reg = 0; reg < 16; ++reg) {
        int gr = node0 + rbase + (reg & 3) + ((reg >> 2) << 3);
        if (gr < N) {
            float v = fmaxf(acc[reg] + bv, 0.f);
            unsigned short h = f2bf(v);
            Xoh[(size_t)gr * 128 + gc] = h;
            Xol[(size_t)gr * 128 + gc] = f2bf(v - bf2f(h));
        }
    }
}

// ---------------- gated output ----------------
__global__ __launch_bounds__(256) void output_kernel(
    const int* __restrict__ samples,
    const float* __restrict__ gate_e,
    const float* __restrict__ gate_r,
    const float* __restrict__ ent_emb,
    const float* __restrict__ rel_emb,
    const unsigned short* __restrict__ ctx2h,
    const unsigned short* __restrict__ ctx2l,
    const float* __restrict__ relctx,
    float* __restrict__ out, int S)
{
    int s = blockIdx.x * 2 + (threadIdx.x >> 7);
    if (s >= S) return;
    int p = blockIdx.y;
    int o = threadIdx.x & 127;
    float v;
    if (p == 1) {
        int idx = samples[s * 3 + 1];
        float g = 1.0f / (1.0f + __expf(-gate_r[o]));
        v = g * rel_emb[idx * 128 + o] + (1.0f - g) * relctx[idx * 128 + o];
    } else {
        int idx = samples[s * 3 + (p == 0 ? 0 : 2)];
        float g = 1.0f / (1.0f + __expf(-gate_e[o]));
        float c = bf2f(ctx2h[(size_t)idx * 128 + o]) + bf2f(ctx2l[(size_t)idx * 128 + o]);
        v = g * ent_emb[(size_t)idx * 128 + o] + (1.0f - g) * c;
    }
    out[(size_t)p * S * 128 + (size_t)s * 128 + o] = v;
}

extern "C" void kernel_launch(void* const* d_in, const int* in_sizes, int n_in,
                              void* d_out, int out_size, void* d_ws, size_t ws_size,
                              hipStream_t stream)
{
    const int*   entity     = (const int*)d_in[0];
    const int*   edge_index = (const int*)d_in[1];
    const int*   edge_type  = (const int*)d_in[2];
    const float* edge_norm  = (const float*)d_in[3];
    const int*   samples    = (const int*)d_in[4];
    const float* DAD        = (const float*)d_in[5];
    const float* ent_emb    = (const float*)d_in[6];
    const float* rel_emb    = (const float*)d_in[7];
    const float* ent_tab    = (const float*)d_in[8];
    const float* rel_tab    = (const float*)d_in[9];
    const float* Wrel       = (const float*)d_in[10];
    const float* gate_e     = (const float*)d_in[11];
    const float* gate_r     = (const float*)d_in[12];
    const float* basis1     = (const float*)d_in[13];
    const float* att1       = (const float*)d_in[14];
    const float* root1      = (const float*)d_in[15];
    const float* bias1      = (const float*)d_in[16];
    const float* basis2     = (const float*)d_in[17];
    const float* att2       = (const float*)d_in[18];
    const float* root2      = (const float*)d_in[19];
    const float* bias2      = (const float*)d_in[20];

    const int N  = in_sizes[0];        // 50000
    const int E  = in_sizes[2];        // 200000
    const int S  = in_sizes[4] / 3;    // 20000
    const int NR = in_sizes[9] / 128;  // 200

    unsigned short* X0h = (unsigned short*)d_ws;       // [N,128] bf16
    unsigned short* X0l = X0h + (size_t)N * 128;
    unsigned short* X1h = X0l + (size_t)N * 128;
    unsigned short* X1l = X1h + (size_t)N * 128;
    float4* an1    = (float4*)(X1l + (size_t)N * 128); // [E+4]
    float4* an2    = an1 + (E + 4);                    // [E+4]
    float* Rc      = (float*)(an2 + (E + 4));          // [NR,128]
    int*   deg     = (int*)(Rc + (size_t)NR * 128);    // [N]
    int*   rstart  = deg + N;                          // [N+1]
    int*   cursor  = rstart + N + 1;                   // [N]
    int*   src_s   = cursor + N;                       // [E+4]
    int*   btot    = src_s + E + 4;                    // [64]
    int*   boff    = btot + 64;                        // [64]
    uintptr_t bt   = ((uintptr_t)(boff + 64) + 15) & ~(uintptr_t)15;
    unsigned short* Bp1h = (unsigned short*)bt;        // [80*128*8] each
    unsigned short* Bp1l = Bp1h + 80 * 128 * 8;
    unsigned short* Bp2h = Bp1l + 80 * 128 * 8;
    unsigned short* Bp2l = Bp2h + 80 * 128 * 8;

    const int egrid = (E + 255) / 256;
    const int lgrid = (N + 31) / 32;
    const int nB    = (N + 1023) / 1024;
    const int x0blocks = (N * 32 + 255) / 256;         // 6250
    const int pgrid = 640 + egrid + x0blocks + NR;     // 7872

    hipMemsetAsync(deg, 0, (size_t)N * sizeof(int), stream);
    prep_kernel<<<pgrid, 256, 0, stream>>>(
        basis1, root1, basis2, root2, Bp1h, Bp1l, Bp2h, Bp2l,
        edge_index, deg, E, ent_tab, entity, X0h, X0l, N,
        DAD, rel_tab, Wrel, Rc, NR);
    scanA_kernel<<<nB, 1024, 0, stream>>>(deg, rstart, btot, N);
    scanB_kernel<<<1, 64, 0, stream>>>(btot, boff, rstart, nB, N);
    scanC_kernel<<<nB, 1024, 0, stream>>>(rstart, cursor, boff, N);
    fill_kernel<<<egrid, 256, 0, stream>>>(edge_index, edge_type, edge_norm, cursor,
                                           att1, att2, src_s, an1, an2, E);

    // ---- layer 1: X1 = relu([agg(X0)|X0] @ W1) ----
    layer_kernel<<<lgrid, 256, 0, stream>>>(X0h, X0l, rstart, src_s, an1,
                                            Bp1h, Bp1l, bias1, X1h, X1l, N);
    // ---- layer 2: X0 = relu([agg(X1)|X1] @ W2) ----
    layer_kernel<<<lgrid, 256, 0, stream>>>(X1h, X1l, rstart, src_s, an2,
                                            Bp2h, Bp2l, bias2, X0h, X0l, N);

    // ---- gated output ----
    output_kernel<<<dim3((S + 1) / 2, 3), 256, 0, stream>>>(
        samples, gate_e, gate_r, ent_emb, rel_emb, X0h, X0l, Rc, (float*)d_out, S);
}

// Round 13
// 291.305 us; speedup vs baseline: 1.0750x; 1.0750x over previous
//
#include <hip/hip_runtime.h>
#include <hip/hip_bf16.h>

typedef short s8v  __attribute__((ext_vector_type(8)));
typedef float f16v __attribute__((ext_vector_type(16)));

__device__ __forceinline__ unsigned short f2bf(float x) {   // RTN-even
    unsigned u = __float_as_uint(x);
    unsigned r = ((u >> 16) & 1u) + 0x7FFFu;
    return (unsigned short)((u + r) >> 16);
}
__device__ __forceinline__ float bf2f(unsigned short h) {
    return __uint_as_float(((unsigned)h) << 16);
}

// ---------------- fused prep: relctx | bprep | hist | x0 ----------------
// Long-latency relctx blocks FIRST so they overlap the wide sections.
__global__ __launch_bounds__(256) void prep_kernel(
    const float* __restrict__ basis1, const float* __restrict__ root1,
    const float* __restrict__ basis2, const float* __restrict__ root2,
    unsigned short* __restrict__ Bp1h, unsigned short* __restrict__ Bp2h,
    const int* __restrict__ edge_index, int* __restrict__ deg, int E,
    const float* __restrict__ tab, const int* __restrict__ entity,
    unsigned short* __restrict__ X0h, unsigned short* __restrict__ X0l, int N,
    const float* __restrict__ DAD, const float* __restrict__ rtab,
    const float* __restrict__ Wrel, float* __restrict__ Rc, int NR,
    int b1, int b2, int b3)     // b1=NR, b2=NR+640, b3=NR+640+egrid
{
    __shared__ float smem[384];
    const int b = blockIdx.x, tid = threadIdx.x;

    if (b < b1) {                        // ---- relctx ----
        float* part = smem;              // [2][128]
        float* r1s  = smem + 256;        // [128]
        int r = b;
        int o = tid & 127, q = tid >> 7;
        float s = 0.f;
        for (int j = q; j < NR; j += 2)
            s = fmaf(DAD[r * NR + j], rtab[j * 128 + o], s);
        part[q * 128 + o] = s;
        __syncthreads();
        if (tid < 128) r1s[tid] = part[tid] + part[128 + tid];
        __syncthreads();
        float s2 = 0.f;
        #pragma unroll 8
        for (int k = q * 64; k < q * 64 + 64; ++k)
            s2 = fmaf(r1s[k], Wrel[k * 128 + o], s2);
        part[q * 128 + o] = s2;
        __syncthreads();
        if (tid < 128)
            Rc[r * 128 + tid] = fmaxf(part[tid] + part[128 + tid], 0.f);
    } else if (b < b2) {                 // ---- B prep (hi only) ----
        int bb = b - b1;
        int layer = bb >= 320;
        int idx = (layer ? bb - 320 : bb) * 256 + tid;
        int n = idx & 127, k = idx >> 7;
        const float* basis = layer ? basis2 : basis1;
        const float* root  = layer ? root2  : root1;
        float v = (k < 512) ? basis[((k & 3) << 14) + ((k >> 2) << 7) + n]
                            : root[((k - 512) << 7) + n];
        size_t pos = (((size_t)(k >> 3) * 128) + n) * 8 + (k & 7);
        (layer ? Bp2h : Bp1h)[pos] = f2bf(v);
    } else if (b < b3) {                 // ---- hist ----
        int e = (b - b2) * 256 + tid;
        if (e < E) atomicAdd(&deg[edge_index[E + e]], 1);
    } else {                             // ---- X0 = tab[entity] hi/lo ----
        int idx = (b - b3) * 256 + tid;
        int n = idx >> 5, l = idx & 31;
        if (n < N) {
            int src = entity[n];
            float4 v = *(const float4*)&tab[(size_t)src * 128 + l * 4];
            ushort4 h, lo;
            h.x = f2bf(v.x); lo.x = f2bf(v.x - bf2f(h.x));
            h.y = f2bf(v.y); lo.y = f2bf(v.y - bf2f(h.y));
            h.z = f2bf(v.z); lo.z = f2bf(v.z - bf2f(h.z));
            h.w = f2bf(v.w); lo.w = f2bf(v.w - bf2f(h.w));
            *(ushort4*)&X0h[(size_t)n * 128 + l * 4] = h;
            *(ushort4*)&X0l[(size_t)n * 128 + l * 4] = lo;
        }
    }
}

// ---------------- CSR scan ----------------
__global__ __launch_bounds__(1024) void scanA_kernel(
    const int* __restrict__ deg, int* __restrict__ row_start,
    int* __restrict__ btot, int N)
{
    __shared__ int wtot[16];
    __shared__ int woff[16];
    const int tid = threadIdx.x, lane = tid & 63, wid = tid >> 6;
    int i = blockIdx.x * 1024 + tid;
    int v = (i < N) ? deg[i] : 0;
    int x = v;
    #pragma unroll
    for (int d = 1; d < 64; d <<= 1) {
        int t = __shfl_up(x, d, 64);
        if (lane >= d) x += t;
    }
    if (lane == 63) wtot[wid] = x;
    __syncthreads();
    if (wid == 0 && lane < 16) {
        int s = wtot[lane];
        int y = s;
        #pragma unroll
        for (int d = 1; d < 16; d <<= 1) {
            int t = __shfl_up(y, d, 16);
            if (lane >= d) y += t;
        }
        woff[lane] = y - s;
        if (lane == 15) btot[blockIdx.x] = y;
    }
    __syncthreads();
    if (i < N) row_start[i] = woff[wid] + (x - v);
}

__global__ __launch_bounds__(64) void scanB_kernel(
    const int* __restrict__ btot, int* __restrict__ boff,
    int* __restrict__ row_start, int nB, int N)
{
    int t = threadIdx.x;
    int v = (t < nB) ? btot[t] : 0;
    int x = v;
    #pragma unroll
    for (int d = 1; d < 64; d <<= 1) {
        int u = __shfl_up(x, d, 64);
        if (t >= d) x += u;
    }
    if (t < nB) boff[t] = x - v;
    if (t == nB - 1) row_start[N] = x;
}

__global__ __launch_bounds__(1024) void scanC_kernel(
    int* __restrict__ row_start, int* __restrict__ cursor,
    const int* __restrict__ boff, int N)
{
    int i = blockIdx.x * 1024 + threadIdx.x;
    if (i < N) {
        int r = row_start[i] + boff[blockIdx.x];
        row_start[i] = r;
        cursor[i]    = r;
    }
}

__global__ __launch_bounds__(256) void fill_kernel(
    const int* __restrict__ edge_index, const int* __restrict__ edge_type,
    const float* __restrict__ edge_norm, int* __restrict__ cursor,
    const float* __restrict__ att1, const float* __restrict__ att2,
    int* __restrict__ src_s, float4* __restrict__ an1, float4* __restrict__ an2, int E)
{
    int e = blockIdx.x * 256 + threadIdx.x;
    if (e >= E) return;
    int dst = edge_index[E + e];
    int et  = edge_type[e];
    float n = edge_norm[e];
    int pos = atomicAdd(&cursor[dst], 1);
    src_s[pos] = edge_index[e];
    float4 a1 = *(const float4*)&att1[(size_t)et * 4];
    float4 a2 = *(const float4*)&att2[(size_t)et * 4];
    an1[pos] = make_float4(n * a1.x, n * a1.y, n * a1.z, n * a1.w);
    an2[pos] = make_float4(n * a2.x, n * a2.y, n * a2.z, n * a2.w);
}

// ---------------- FUSED layer: Xout = relu([agg(X)|X] @ B + bias) ----------------
// Block = 32 nodes, 256 threads. Phase A: interleaved 4-node edge gather ->
// LDS fragment-packed (slot = n ^ (kh&31)); one barrier. Phase B: barrier-free
// MFMA stream; B (plain bf16) double-buffered global->register.
__global__ __launch_bounds__(256) void layer_kernel(
    const unsigned short* __restrict__ Xh,    // [N,128] bf16 hi
    const unsigned short* __restrict__ Xl,    // [N,128] bf16 lo
    const int* __restrict__ row_start,
    const int* __restrict__ src_s,
    const float4* __restrict__ an,
    const unsigned short* __restrict__ Bph,   // packed [80][128][8] bf16
    const float* __restrict__ bias,
    unsigned short* __restrict__ Xoh,
    unsigned short* __restrict__ Xol,
    int N)
{
    __shared__ unsigned short Whi[80 * 32 * 8];   // 40 KB
    __shared__ unsigned short Wlo[16 * 32 * 8];   // 8 KB

    const int tid   = threadIdx.x;
    const int node0 = blockIdx.x * 32;

    // ---- phase A1: interleaved gather for 4 nodes per 32-lane group ----
    {
        int g = tid >> 5, l = tid & 31;     // lane l covers dims 4l..4l+3
        int nb = node0 + g * 4;
        int s0a[4], s1a[4];
        #pragma unroll
        for (int i = 0; i < 4; ++i) {
            int gn = nb + i;
            bool ok = gn < N;
            s0a[i] = ok ? row_start[gn] : 0;
            s1a[i] = ok ? row_start[gn + 1] : 0;
        }
        float acc[4][4][4];                 // [node][d][b]
        #pragma unroll
        for (int i = 0; i < 4; ++i)
            #pragma unroll
            for (int d = 0; d < 4; ++d)
                #pragma unroll
                for (int c = 0; c < 4; ++c) acc[i][d][c] = 0.f;

        int need = 0;
        #pragma unroll
        for (int i = 0; i < 4; ++i) need = max(need, s1a[i] - s0a[i]);

        for (int p = 0; p < need; p += 4) {
            #pragma unroll
            for (int i = 0; i < 4; ++i) {
                int q0 = s0a[i] + p;
                if (q0 < s1a[i]) {
                    int se = s1a[i] - 1;
                    int q1 = min(q0 + 1, se);
                    int q2 = min(q0 + 2, se);
                    int q3 = min(q0 + 3, se);
                    int sA = src_s[q0], sB = src_s[q1];
                    int sC = src_s[q2], sD = src_s[q3];
                    float4 aA = an[q0], aB = an[q1];
                    float4 aC = an[q2], aD = an[q3];
                    if (q0 + 1 > se) aB = make_float4(0.f, 0.f, 0.f, 0.f);
                    if (q0 + 2 > se) aC = make_float4(0.f, 0.f, 0.f, 0.f);
                    if (q0 + 3 > se) aD = make_float4(0.f, 0.f, 0.f, 0.f);
                    ushort4 hA = *(const ushort4*)&Xh[(size_t)sA * 128 + (l << 2)];
                    ushort4 hB = *(const ushort4*)&Xh[(size_t)sB * 128 + (l << 2)];
                    ushort4 hC = *(const ushort4*)&Xh[(size_t)sC * 128 + (l << 2)];
                    ushort4 hD = *(const ushort4*)&Xh[(size_t)sD * 128 + (l << 2)];
                    float xsA[4] = {bf2f(hA.x), bf2f(hA.y), bf2f(hA.z), bf2f(hA.w)};
                    float xsB[4] = {bf2f(hB.x), bf2f(hB.y), bf2f(hB.z), bf2f(hB.w)};
                    float xsC[4] = {bf2f(hC.x), bf2f(hC.y), bf2f(hC.z), bf2f(hC.w)};
                    float xsD[4] = {bf2f(hD.x), bf2f(hD.y), bf2f(hD.z), bf2f(hD.w)};
                    #pragma unroll
                    for (int d = 0; d < 4; ++d) {
                        acc[i][d][0] = fmaf(aA.x, xsA[d], fmaf(aB.x, xsB[d], fmaf(aC.x, xsC[d], fmaf(aD.x, xsD[d], acc[i][d][0]))));
                        acc[i][d][1] = fmaf(aA.y, xsA[d], fmaf(aB.y, xsB[d], fmaf(aC.y, xsC[d], fmaf(aD.y, xsD[d], acc[i][d][1]))));
                        acc[i][d][2] = fmaf(aA.z, xsA[d], fmaf(aB.z, xsB[d], fmaf(aC.z, xsC[d], fmaf(aD.z, xsD[d], acc[i][d][2]))));
                        acc[i][d][3] = fmaf(aA.w, xsA[d], fmaf(aB.w, xsB[d], fmaf(aC.w, xsC[d], fmaf(aD.w, xsD[d], acc[i][d][3]))));
                    }
                }
            }
        }
        #pragma unroll
        for (int i = 0; i < 4; ++i) {
            int n = g * 4 + i;
            float inv = 1.0f / fmaxf((float)(s1a[i] - s0a[i]), 1.0f);
            #pragma unroll
            for (int d = 0; d < 4; ++d) {
                int kh   = 2 * l + (d >> 1);
                int slot = n ^ (kh & 31);
                ushort4 h;
                h.x = f2bf(acc[i][d][0] * inv);
                h.y = f2bf(acc[i][d][1] * inv);
                h.z = f2bf(acc[i][d][2] * inv);
                h.w = f2bf(acc[i][d][3] * inv);
                *(ushort4*)&Whi[(kh * 32 + slot) * 8 + (d & 1) * 4] = h;
            }
        }
    }

    // ---- phase A2: X hi/lo rows (k 512..639), kh 64..79 ----
    {
        int r  = tid >> 3;
        int kq = (tid & 7) * 16;
        int gn = node0 + r;
        #pragma unroll
        for (int i = 0; i < 2; ++i) {
            int kh   = 64 + (tid & 7) * 2 + i;
            int slot = r ^ (kh & 31);
            s8v h8 = {0,0,0,0,0,0,0,0}, l8 = {0,0,0,0,0,0,0,0};
            if (gn < N) {
                h8 = *(const s8v*)&Xh[(size_t)gn * 128 + kq + i * 8];
                l8 = *(const s8v*)&Xl[(size_t)gn * 128 + kq + i * 8];
            }
            *(s8v*)&Whi[(kh * 32 + slot) * 8] = h8;
            *(s8v*)&Wlo[((kh - 64) * 32 + slot) * 8] = l8;
        }
    }
    __syncthreads();

    // ---- phase B: barrier-free MFMA stream, B hi-only ----
    const int lane = tid & 63, wv = tid >> 6;
    const int m    = lane & 31;
    const int kh8  = lane >> 5;
    const int c0   = wv << 5;

    f16v acc;
    #pragma unroll
    for (int i = 0; i < 16; ++i) acc[i] = 0.f;

    s8v Bb[2][4];
    auto loadB4 = [&](int g, int buf) {
        #pragma unroll
        for (int q = 0; q < 4; ++q) {
            int khg = (g * 4 + q) * 2 + kh8;
            size_t off = ((size_t)khg * 128 + c0 + m) * 8;
            Bb[buf][q] = *(const s8v*)&Bph[off];
        }
    };
    loadB4(0, 0);

    #pragma unroll
    for (int g = 0; g < 10; ++g) {
        int buf = g & 1;
        if (g < 9) loadB4(g + 1, buf ^ 1);
        #pragma unroll
        for (int q = 0; q < 4; ++q) {
            int s    = g * 4 + q;
            int khg  = s * 2 + kh8;
            int slot = m ^ (khg & 31);
            s8v aH = *(const s8v*)&Whi[(khg * 32 + slot) * 8];
            if (s >= 32) {
                s8v aL = *(const s8v*)&Wlo[((khg - 64) * 32 + slot) * 8];
                acc = __builtin_amdgcn_mfma_f32_32x32x16_bf16(aL, Bb[buf][q], acc, 0, 0, 0);
            }
            acc = __builtin_amdgcn_mfma_f32_32x32x16_bf16(aH, Bb[buf][q], acc, 0, 0, 0);
        }
    }

    // epilogue: 32x32 C/D: col = lane&31, row = (reg&3) + 8*(reg>>2) + 4*(lane>>5)
    int gc = c0 + m;
    float bv = bias[gc];
    const int rbase = kh8 << 2;
    #pragma unroll
    for (int reg = 0; reg < 16; ++reg) {
        int gr = node0 + rbase + (reg & 3) + ((reg >> 2) << 3);
        if (gr < N) {
            float v = fmaxf(acc[reg] + bv, 0.f);
            unsigned short h = f2bf(v);
            Xoh[(size_t)gr * 128 + gc] = h;
            Xol[(size_t)gr * 128 + gc] = f2bf(v - bf2f(h));
        }
    }
}

// ---------------- gated output ----------------
__global__ __launch_bounds__(256) void output_kernel(
    const int* __restrict__ samples,
    const float* __restrict__ gate_e,
    const float* __restrict__ gate_r,
    const float* __restrict__ ent_emb,
    const float* __restrict__ rel_emb,
    const unsigned short* __restrict__ ctx2h,
    const unsigned short* __restrict__ ctx2l,
    const float* __restrict__ relctx,
    float* __restrict__ out, int S)
{
    int s = blockIdx.x * 2 + (threadIdx.x >> 7);
    if (s >= S) return;
    int p = blockIdx.y;
    int o = threadIdx.x & 127;
    float v;
    if (p == 1) {
        int idx = samples[s * 3 + 1];
        float g = 1.0f / (1.0f + __expf(-gate_r[o]));
        v = g * rel_emb[idx * 128 + o] + (1.0f - g) * relctx[idx * 128 + o];
    } else {
        int idx = samples[s * 3 + (p == 0 ? 0 : 2)];
        float g = 1.0f / (1.0f + __expf(-gate_e[o]));
        float c = bf2f(ctx2h[(size_t)idx * 128 + o]) + bf2f(ctx2l[(size_t)idx * 128 + o]);
        v = g * ent_emb[(size_t)idx * 128 + o] + (1.0f - g) * c;
    }
    out[(size_t)p * S * 128 + (size_t)s * 128 + o] = v;
}

extern "C" void kernel_launch(void* const* d_in, const int* in_sizes, int n_in,
                              void* d_out, int out_size, void* d_ws, size_t ws_size,
                              hipStream_t stream)
{
    const int*   entity     = (const int*)d_in[0];
    const int*   edge_index = (const int*)d_in[1];
    const int*   edge_type  = (const int*)d_in[2];
    const float* edge_norm  = (const float*)d_in[3];
    const int*   samples    = (const int*)d_in[4];
    const float* DAD        = (const float*)d_in[5];
    const float* ent_emb    = (const float*)d_in[6];
    const float* rel_emb    = (const float*)d_in[7];
    const float* ent_tab    = (const float*)d_in[8];
    const float* rel_tab    = (const float*)d_in[9];
    const float* Wrel       = (const float*)d_in[10];
    const float* gate_e     = (const float*)d_in[11];
    const float* gate_r     = (const float*)d_in[12];
    const float* basis1     = (const float*)d_in[13];
    const float* att1       = (const float*)d_in[14];
    const float* root1      = (const float*)d_in[15];
    const float* bias1      = (const float*)d_in[16];
    const float* basis2     = (const float*)d_in[17];
    const float* att2       = (const float*)d_in[18];
    const float* root2      = (const float*)d_in[19];
    const float* bias2      = (const float*)d_in[20];

    const int N  = in_sizes[0];        // 50000
    const int E  = in_sizes[2];        // 200000
    const int S  = in_sizes[4] / 3;    // 20000
    const int NR = in_sizes[9] / 128;  // 200

    unsigned short* X0h = (unsigned short*)d_ws;       // [N,128] bf16
    unsigned short* X0l = X0h + (size_t)N * 128;
    unsigned short* X1h = X0l + (size_t)N * 128;
    unsigned short* X1l = X1h + (size_t)N * 128;
    float4* an1    = (float4*)(X1l + (size_t)N * 128); // [E+4]
    float4* an2    = an1 + (E + 4);                    // [E+4]
    float* Rc      = (float*)(an2 + (E + 4));          // [NR,128]
    int*   deg     = (int*)(Rc + (size_t)NR * 128);    // [N]
    int*   rstart  = deg + N;                          // [N+1]
    int*   cursor  = rstart + N + 1;                   // [N]
    int*   src_s   = cursor + N;                       // [E+4]
    int*   btot    = src_s + E + 4;                    // [64]
    int*   boff    = btot + 64;                        // [64]
    uintptr_t bt   = ((uintptr_t)(boff + 64) + 15) & ~(uintptr_t)15;
    unsigned short* Bp1h = (unsigned short*)bt;        // [80*128*8]
    unsigned short* Bp2h = Bp1h + 80 * 128 * 8;

    const int egrid = (E + 255) / 256;
    const int lgrid = (N + 31) / 32;
    const int nB    = (N + 1023) / 1024;
    const int x0blocks = (N * 32 + 255) / 256;
    const int b1 = NR;
    const int b2 = NR + 640;
    const int b3 = b2 + egrid;
    const int pgrid = b3 + x0blocks;

    hipMemsetAsync(deg, 0, (size_t)N * sizeof(int), stream);
    prep_kernel<<<pgrid, 256, 0, stream>>>(
        basis1, root1, basis2, root2, Bp1h, Bp2h,
        edge_index, deg, E, ent_tab, entity, X0h, X0l, N,
        DAD, rel_tab, Wrel, Rc, NR, b1, b2, b3);
    scanA_kernel<<<nB, 1024, 0, stream>>>(deg, rstart, btot, N);
    scanB_kernel<<<1, 64, 0, stream>>>(btot, boff, rstart, nB, N);
    scanC_kernel<<<nB, 1024, 0, stream>>>(rstart, cursor, boff, N);
    fill_kernel<<<egrid, 256, 0, stream>>>(edge_index, edge_type, edge_norm, cursor,
                                           att1, att2, src_s, an1, an2, E);

    // ---- layer 1: X1 = relu([agg(X0)|X0] @ W1) ----
    layer_kernel<<<lgrid, 256, 0, stream>>>(X0h, X0l, rstart, src_s, an1,
                                            Bp1h, bias1, X1h, X1l, N);
    // ---- layer 2: X0 = relu([agg(X1)|X1] @ W2) ----
    layer_kernel<<<lgrid, 256, 0, stream>>>(X1h, X1l, rstart, src_s, an2,
                                            Bp2h, bias2, X0h, X0l, N);

    // ---- gated output ----
    output_kernel<<<dim3((S + 1) / 2, 3), 256, 0, stream>>>(
        samples, gate_e, gate_r, ent_emb, rel_emb, X0h, X0l, Rc, (float*)d_out, S);
}